// Round 22
// baseline (390.561 us; speedup 1.0000x reference)
//
#include <hip/hip_runtime.h>
#include <math.h>

#define CCH    512
#define HWN    4096
#define NPIX   65536
#define OC3    1536
#define QSCALE 0.125f
#define LN_EPS 1e-5f

typedef _Float16 h16;
typedef h16  f16x8 __attribute__((ext_vector_type(8)));
typedef h16  f16x4 __attribute__((ext_vector_type(4)));
typedef float f32x4 __attribute__((ext_vector_type(4)));

__device__ __forceinline__ float waveReduceSum(float v) {
#pragma unroll
    for (int off = 32; off; off >>= 1) v += __shfl_xor(v, off);
    return v;
}

__device__ __forceinline__ void gl_lds16(const void* g, void* l) {
    __builtin_amdgcn_global_load_lds((const __attribute__((address_space(1))) void*)g,
                                     (__attribute__((address_space(3))) void*)l, 16, 0, 0);
}

// ---------------------------------------------------------------------------
// fused: z<16  -> fp32 x -> transposed fp16 [16][4096][512] + LN partials
//        z==16 -> weight prep (wave = one row)
__global__ __launch_bounds__(256) void transpose_prep(const float* __restrict__ src,
                                                      h16* __restrict__ dhi,
                                                      float* __restrict__ psum,
                                                      float* __restrict__ psq,
                                                      const float* __restrict__ w_qkv,
                                                      const float* __restrict__ g_ln,
                                                      const float* __restrict__ w_out,
                                                      h16* __restrict__ wg_h,
                                                      float* __restrict__ s,
                                                      h16* __restrict__ wo_h) {
    __shared__ float tile[64][65];
    __shared__ float ps1[4][64], ps2[4][64];
    const int t = threadIdx.x;

    if (blockIdx.z == 16) {
        const int o = (blockIdx.x + 64 * blockIdx.y) * 4 + (t >> 6);
        const int lane = t & 63;
        if (o < OC3) {
            float sum = 0.f;
#pragma unroll
            for (int j = 0; j < 8; ++j) {
                const int c = lane + j * 64;
                const float w = w_qkv[(size_t)o * CCH + c] * g_ln[c];
                wg_h[(size_t)o * CCH + c] = (h16)(w * 64.f);
                sum += w;
            }
            sum = waveReduceSum(sum);
            if (lane == 0) s[o] = sum;
        } else {
            const int r = o - OC3;
#pragma unroll
            for (int j = 0; j < 8; ++j) {
                const int c = lane + j * 64;
                wo_h[(size_t)r * CCH + c] = (h16)(w_out[(size_t)r * CCH + c] * 64.f);
            }
        }
        return;
    }

    const int b = blockIdx.z, c0 = blockIdx.y * 64, p0 = blockIdx.x * 64;
    const float* sb = src + ((size_t)b * CCH + c0) * HWN + p0;
    const int rc = t >> 4, cc4 = (t & 15) * 4;
#pragma unroll
    for (int ps = 0; ps < 4; ++ps) {
        const float4 v = *(const float4*)(sb + (size_t)(rc + ps * 16) * HWN + cc4);
        tile[rc + ps * 16][cc4 + 0] = v.x;
        tile[rc + ps * 16][cc4 + 1] = v.y;
        tile[rc + ps * 16][cc4 + 2] = v.z;
        tile[rc + ps * 16][cc4 + 3] = v.w;
    }
    __syncthreads();
    {
        const int q = t >> 6, px = t & 63;
        float s1 = 0.f, s2 = 0.f;
#pragma unroll
        for (int c = q * 16; c < q * 16 + 16; ++c) {
            const float v = tile[c][px];
            s1 += v; s2 += v * v;
        }
        ps1[q][px] = s1; ps2[q][px] = s2;
    }
    const int pr0 = t >> 3, cs = (t & 7) * 8;
#pragma unroll
    for (int ps = 0; ps < 2; ++ps) {
        const int pr = pr0 + ps * 32;
        f16x8 vh;
#pragma unroll
        for (int q = 0; q < 8; ++q) vh[q] = (h16)tile[cs + q][pr];
        const size_t o = ((size_t)b * HWN + p0 + pr) * CCH + c0 + cs;
        *(f16x8*)(dhi + o) = vh;
    }
    __syncthreads();
    if (t < 64) {
        const float s1 = ps1[0][t] + ps1[1][t] + ps1[2][t] + ps1[3][t];
        const float s2 = ps2[0][t] + ps2[1][t] + ps2[2][t] + ps2[3][t];
        const size_t gp = (size_t)b * HWN + p0 + t;
        psum[(size_t)(c0 >> 6) * NPIX + gp] = s1;
        psq [(size_t)(c0 >> 6) * NPIX + gp] = s2;
    }
}

// ---------------------------------------------------------------------------
// QKV GEMM, counted-vmcnt pipeline: 128x256 tile, 8 waves of 64x64, BK=32 x
// 16 steps, 3-buffer LDS ring (72 KiB -> 2 blocks/CU), 2-deep prefetch.
// Per step: vmcnt(3) [tile t landed; newest 3 = tile t+2] -> barrier ->
// ds_read frags -> issue STAGE(t+2) -> 16 MFMA. No vmcnt(0) drain in loop.
// Single fp16 (A x64 scaled). LN stats fused (before staging, drained).
// out fp16 = rstd[p]*(acc/64 - mean[p]*s[o]).
__global__ __launch_bounds__(512, 1) void qkv_gemm(const h16* __restrict__ Ahg,
                                                   const h16* __restrict__ Bhg,
                                                   const float* __restrict__ sv,
                                                   const float* __restrict__ psum,
                                                   const float* __restrict__ psq,
                                                   h16* __restrict__ qout) {
    __shared__ __align__(16) h16 lds[36864];   // 3 bufs x 12288 halfs (24 KB)
    __shared__ float mnS[256], rsS[256];
    const int tid = threadIdx.x;
    const int om = blockIdx.x * 128;
    const int by0 = blockIdx.y;
    const int by  = (by0 & 7) * 32 + (by0 >> 3);   // bijective XCD chunking
    const int p0  = by * 256;

    const int srow = tid >> 2;
    const int skh  = ((tid & 3) ^ (srow & 3)) * 8;
    const size_t a0 = (size_t)(om + srow) * CCH + skh;
    const size_t b0 = (size_t)(p0 + srow) * CCH + skh;

    const int lane = tid & 63;
    const int wv = tid >> 6;
    const int wm = (wv >> 2) * 64, wn = (wv & 3) * 64;
    const int lr = lane & 15, kg = lane >> 4;
    const int swz = (kg ^ (lr & 3)) * 8;

    f32x4 acc[4][4];
#pragma unroll
    for (int i = 0; i < 4; ++i)
#pragma unroll
        for (int j = 0; j < 4; ++j) acc[i][j] = {0.f, 0.f, 0.f, 0.f};

    // LN stats first; the closing barrier drains all vmem before staging,
    // keeping the loop's vmcnt arithmetic exact.
    if (tid < 256) {
        const int gp = p0 + tid;
        float s1 = 0.f, s2 = 0.f;
#pragma unroll
        for (int cb = 0; cb < 8; ++cb) {
            s1 += psum[(size_t)cb * NPIX + gp];
            s2 += psq [(size_t)cb * NPIX + gp];
        }
        const float m = s1 * (1.f / 512.f);
        float var = s2 * (1.f / 512.f) - m * m;
        var = fmaxf(var, 0.f);
        mnS[tid] = m;
        rsS[tid] = rsqrtf(var + LN_EPS);
    }
    __syncthreads();

#define BUF(k) (lds + (k) * 12288)
#define STAGE(T)                                                        \
    do {                                                                \
        h16* Lb = BUF((T) % 3);                                         \
        const int kc_ = (T) * 32;                                       \
        gl_lds16(Ahg + a0 + kc_,             Lb + tid * 8);             \
        gl_lds16(Bhg + b0 + kc_,             Lb + 4096 + tid * 8);      \
        gl_lds16(Bhg + b0 + kc_ + 128 * CCH, Lb + 8192 + tid * 8);      \
    } while (0)

    STAGE(0);
    STAGE(1);

#pragma unroll 1
    for (int t = 0; t < 16; ++t) {
        if (t == 15) asm volatile("s_waitcnt vmcnt(0)" ::: "memory");
        else         asm volatile("s_waitcnt vmcnt(3)" ::: "memory");
        __builtin_amdgcn_sched_barrier(0);
        __builtin_amdgcn_s_barrier();
        __builtin_amdgcn_sched_barrier(0);
        const h16* Rb = BUF(t % 3);
        f16x8 af[4], bf[4];
#pragma unroll
        for (int i = 0; i < 4; ++i) {
            af[i] = *(const f16x8*)(Rb + (wm + i * 16 + lr) * 32 + swz);
            bf[i] = *(const f16x8*)(Rb + 4096 + (wn + i * 16 + lr) * 32 + swz);
        }
        if (t + 2 < 16) STAGE(t + 2);   // -> buf (t-1)%3: reads done pre-barrier
        __builtin_amdgcn_s_setprio(1);
#pragma unroll
        for (int i = 0; i < 4; ++i)
#pragma unroll
            for (int j = 0; j < 4; ++j)
                acc[i][j] = __builtin_amdgcn_mfma_f32_16x16x32_f16(af[i], bf[j], acc[i][j], 0, 0, 0);
        __builtin_amdgcn_s_setprio(0);
    }
#undef STAGE
#undef BUF

    const int b = p0 >> 12, hw0 = p0 & 4095;
    float mn[4], rs[4];
#pragma unroll
    for (int j = 0; j < 4; ++j) {
        const int px = wn + j * 16 + lr;
        mn[j] = mnS[px]; rs[j] = rsS[px];
    }
#pragma unroll
    for (int i = 0; i < 4; ++i)
#pragma unroll
        for (int r = 0; r < 4; ++r) {
            const int o = om + wm + i * 16 + kg * 4 + r;
            const float so = sv[o];
            h16* dst = qout + ((size_t)b * OC3 + o) * HWN;
#pragma unroll
            for (int j = 0; j < 4; ++j) {
                const int hw = hw0 + wn + j * 16 + lr;
                dst[hw] = (h16)(rs[j] * (acc[i][j][r] * (1.f / 64.f) - mn[j] * so));
            }
        }
}

// ---------------------------------------------------------------------------
// MFMA context partial over a 256-pixel chunk (1 wave, no LDS, no barriers).
__global__ __launch_bounds__(64) void ctx_partial(const h16* __restrict__ qkv16,
                                                  float* __restrict__ ctp) {
    const int bh = blockIdx.y, ci = blockIdx.x;
    const int b = bh >> 3, h = bh & 7;
    const h16* kb = qkv16 + ((size_t)b * OC3 + CCH  + h * 64) * HWN;
    const h16* vb = qkv16 + ((size_t)b * OC3 + 1024 + h * 64) * HWN;
    const int lane = threadIdx.x;
    const int lr = lane & 15, kg = lane >> 4;
    const int nbase = ci * 256 + kg * 8;

    float m[4] = {-1e30f, -1e30f, -1e30f, -1e30f};
#pragma unroll 1
    for (int c = 0; c < 8; ++c) {
        const int n0 = nbase + c * 32;
#pragma unroll
        for (int i = 0; i < 4; ++i) {
            const f16x8 kv = *(const f16x8*)(kb + (size_t)(i * 16 + lr) * HWN + n0);
#pragma unroll
            for (int u = 0; u < 8; ++u) m[i] = fmaxf(m[i], (float)kv[u]);
        }
    }
#pragma unroll
    for (int i = 0; i < 4; ++i) {
        m[i] = fmaxf(m[i], __shfl_xor(m[i], 16));
        m[i] = fmaxf(m[i], __shfl_xor(m[i], 32));
    }

    float z[4] = {0.f, 0.f, 0.f, 0.f};
    f32x4 acc[4][4];
#pragma unroll
    for (int i = 0; i < 4; ++i)
#pragma unroll
        for (int j = 0; j < 4; ++j) acc[i][j] = {0.f, 0.f, 0.f, 0.f};

#pragma unroll 1
    for (int c = 0; c < 8; ++c) {
        const int n0 = nbase + c * 32;
        f16x8 ke[4], vf[4];
#pragma unroll
        for (int j = 0; j < 4; ++j)
            vf[j] = *(const f16x8*)(vb + (size_t)(j * 16 + lr) * HWN + n0);
#pragma unroll
        for (int i = 0; i < 4; ++i) {
            const f16x8 kv = *(const f16x8*)(kb + (size_t)(i * 16 + lr) * HWN + n0);
            f16x8 t;
#pragma unroll
            for (int u = 0; u < 8; ++u) {
                const float e = __expf((float)kv[u] - m[i]);
                z[i] += e;
                t[u] = (h16)e;
            }
            ke[i] = t;
        }
#pragma unroll
        for (int i = 0; i < 4; ++i)
#pragma unroll
            for (int j = 0; j < 4; ++j)
                acc[i][j] = __builtin_amdgcn_mfma_f32_16x16x32_f16(ke[i], vf[j], acc[i][j], 0, 0, 0);
    }
#pragma unroll
    for (int i = 0; i < 4; ++i) {
        z[i] += __shfl_xor(z[i], 16);
        z[i] += __shfl_xor(z[i], 32);
    }
    float* dst = ctp + ((size_t)bh * 16 + ci) * 4224;
#pragma unroll
    for (int i = 0; i < 4; ++i)
#pragma unroll
        for (int j = 0; j < 4; ++j)
#pragma unroll
            for (int r = 0; r < 4; ++r)
                dst[(i * 16 + kg * 4 + r) * 64 + j * 16 + lr] = acc[i][j][r];
    if (kg == 0)
#pragma unroll
        for (int i = 0; i < 4; ++i) {
            dst[4096 + i * 16 + lr] = z[i];
            dst[4160 + i * 16 + lr] = m[i];
        }
}

// ---------------------------------------------------------------------------
// combine 16 chunk partials with exp(m_loc - M) rescale, normalize, and emit
// TRANSPOSED fp16: ctt[e][d]
__global__ __launch_bounds__(256) void ctx_reduce(const float* __restrict__ ctp,
                                                  h16* __restrict__ ctt) {
    __shared__ float w[16][64];
    __shared__ float rz[64];
    const int bh = blockIdx.x;
    const int tid = threadIdx.x;
    const float* src = ctp + (size_t)bh * 16 * 4224;
    if (tid < 64) {
        float M = -1e30f;
#pragma unroll
        for (int ci = 0; ci < 16; ++ci)
            M = fmaxf(M, src[(size_t)ci * 4224 + 4160 + tid]);
        float Z = 0.f;
#pragma unroll
        for (int ci = 0; ci < 16; ++ci) {
            const float ww = __expf(src[(size_t)ci * 4224 + 4160 + tid] - M);
            w[ci][tid] = ww;
            Z += ww * src[(size_t)ci * 4224 + 4096 + tid];
        }
        rz[tid] = 1.f / Z;
    }
    __syncthreads();
    h16* dstt = ctt + (size_t)bh * 4096;
    for (int e4 = tid * 4; e4 < 4096; e4 += 1024) {
        const int d = e4 >> 6, e0 = e4 & 63;
        float4 sum = make_float4(0.f, 0.f, 0.f, 0.f);
#pragma unroll
        for (int ci = 0; ci < 16; ++ci) {
            const float4 v = *(const float4*)(src + (size_t)ci * 4224 + e4);
            const float ww = w[ci][d];
            sum.x += ww * v.x; sum.y += ww * v.y;
            sum.z += ww * v.z; sum.w += ww * v.w;
        }
        const float r = rz[d];
        dstt[(e0 + 0) * 64 + d] = (h16)(sum.x * r);
        dstt[(e0 + 1) * 64 + d] = (h16)(sum.y * r);
        dstt[(e0 + 2) * 64 + d] = (h16)(sum.z * r);
        dstt[(e0 + 3) * 64 + d] = (h16)(sum.w * r);
    }
}

// ---------------------------------------------------------------------------
// MEGA out kernel: per head h = 0..7:
//   A1: q regs (prefetched) -> qt[px][d] LDS
//   A2: q-softmax over d (4 lanes/px), qtilde fp16 in place (x 512*QSCALE)
//   A3: PV MFMA (A = ctt reg frags, B = qtilde) -> at-tile fp16 back into qt
//   Apf: prefetch q(h+1) into regs (hides under A4's MFMA + staging)
//   A4: 2 GEMM K-steps: acc += wo(s) . at-tile
// epilogue: y = acc*2^-27 + bias; channel-LN; out = LN(y)*g_out + x.
__global__ __launch_bounds__(512) void out_fused(const h16* __restrict__ wo_hi,
                                                 const h16* __restrict__ qkv16,
                                                 const h16* __restrict__ ctt,
                                                 const float* __restrict__ b_out,
                                                 const float* __restrict__ g_out,
                                                 const float* __restrict__ x,
                                                 float* __restrict__ out) {
    __shared__ __align__(16) h16 Alds[512 * 32];   // 32 KB, one K-step
    __shared__ __align__(16) h16 qt[128][72];      // 18.4 KB; q / qtilde / at-tile
    __shared__ float red1[4][128], red2[4][128];
    __shared__ float mnS[128], rsS[128];

    const int tid = threadIdx.x;
    const int p0 = blockIdx.x * 128;
    const int b = p0 >> 12, hw0 = p0 & 4095;

    const int trow = tid >> 2;
    const int skh  = ((tid & 3) ^ (trow & 3)) * 8;
    const size_t aoff = (size_t)trow * CCH + skh;
    const int wofs = (tid >> 6) * 512;

    const int wv = tid >> 6;
    const int lane = tid & 63;
    const int lr = lane & 15, kg = lane >> 4;
    const int wm = (wv >> 1) * 128, wn = (wv & 1) * 64;   // GEMM map
    const int swz = (kg ^ (lr & 3)) * 8;
    const int pv_e0 = (wv & 3) * 16, pv_ph = (wv >> 2) * 64;   // PV map
    const int sm_px = tid >> 2, sm_d0 = (tid & 3) * 16;        // softmax map
    const int ql_d = tid >> 3, ql_px = (tid & 7) * 16;         // q-load map

    f32x4 acc[8][4];
#pragma unroll
    for (int i = 0; i < 8; ++i)
#pragma unroll
        for (int j = 0; j < 4; ++j) acc[i][j] = {0.f, 0.f, 0.f, 0.f};

#define STAGEF(S)                                                           \
    do {                                                                    \
        const int kc_ = (S) * 32;                                           \
        gl_lds16(wo_hi + aoff + kc_,               Alds + wofs);            \
        gl_lds16(wo_hi + aoff + kc_ + 128 * CCH,   Alds + 4096 + wofs);     \
        gl_lds16(wo_hi + aoff + kc_ + 256 * CCH,   Alds + 8192 + wofs);     \
        gl_lds16(wo_hi + aoff + kc_ + 384 * CCH,   Alds + 12288 + wofs);    \
    } while (0)

    STAGEF(0);

    // prefetch q(h=0) into registers
    f16x8 q0, q1;
    {
        const h16* qb = qkv16 + ((size_t)b * OC3) * HWN + hw0;
        q0 = *(const f16x8*)(qb + (size_t)ql_d * HWN + ql_px);
        q1 = *(const f16x8*)(qb + (size_t)ql_d * HWN + ql_px + 8);
    }

#pragma unroll 1
    for (int h = 0; h < 8; ++h) {
        // ---- A1: q regs -> qt[px][d] ----
#pragma unroll
        for (int u = 0; u < 8; ++u) {
            qt[ql_px + u][ql_d]     = q0[u];
            qt[ql_px + 8 + u][ql_d] = q1[u];
        }
        __syncthreads();
        // ---- A2: softmax over d ----
        {
            float qv[16];
            float mx = -1e30f;
#pragma unroll
            for (int dd = 0; dd < 16; ++dd) {
                qv[dd] = (float)qt[sm_px][sm_d0 + dd];
                mx = fmaxf(mx, qv[dd]);
            }
            mx = fmaxf(mx, __shfl_xor(mx, 1));
            mx = fmaxf(mx, __shfl_xor(mx, 2));
            float sm = 0.f;
#pragma unroll
            for (int dd = 0; dd < 16; ++dd) {
                qv[dd] = __expf(qv[dd] - mx);
                sm += qv[dd];
            }
            sm += __shfl_xor(sm, 1);
            sm += __shfl_xor(sm, 2);
            const float sc = 512.f * QSCALE / sm;
#pragma unroll
            for (int dd = 0; dd < 16; ++dd)
                qt[sm_px][sm_d0 + dd] = (h16)(qv[dd] * sc);
        }
        __syncthreads();
        // ---- A3: PV MFMA -> at-tile ----
        {
            const h16* cb = ctt + ((size_t)(b * 8 + h)) * 4096 + (pv_e0 + lr) * 64 + kg * 8;
            const f16x8 af0 = *(const f16x8*)(cb);
            const f16x8 af1 = *(const f16x8*)(cb + 32);
            f32x4 acc4[4];
#pragma unroll
            for (int j = 0; j < 4; ++j) acc4[j] = {0.f, 0.f, 0.f, 0.f};
#pragma unroll
            for (int j = 0; j < 4; ++j) {
                const int px = pv_ph + j * 16 + lr;
                const f16x8 bf0 = *(const f16x8*)(&qt[px][kg * 8]);
                const f16x8 bf1 = *(const f16x8*)(&qt[px][32 + kg * 8]);
                acc4[j] = __builtin_amdgcn_mfma_f32_16x16x32_f16(af0, bf0, acc4[j], 0, 0, 0);
                acc4[j] = __builtin_amdgcn_mfma_f32_16x16x32_f16(af1, bf1, acc4[j], 0, 0, 0);
            }
            __syncthreads();   // qtilde reads done; qt becomes at-tile
#pragma unroll
            for (int j = 0; j < 4; ++j) {
                f16x4 o4;
                o4[0] = (h16)acc4[j][0]; o4[1] = (h16)acc4[j][1];
                o4[2] = (h16)acc4[j][2]; o4[3] = (h16)acc4[j][3];
                *(f16x4*)(&qt[pv_ph + j * 16 + lr][pv_e0 + kg * 4]) = o4;
            }
        }
        // ---- Apf: prefetch q(h+1) regs (in flight across A4) ----
        if (h < 7) {
            const h16* qb = qkv16 + ((size_t)b * OC3 + (h + 1) * 64) * HWN + hw0;
            q0 = *(const f16x8*)(qb + (size_t)ql_d * HWN + ql_px);
            q1 = *(const f16x8*)(qb + (size_t)ql_d * HWN + ql_px + 8);
        }
        // ---- A4: 2 GEMM K-steps consuming at-tile ----
#pragma unroll 1
        for (int ss = 0; ss < 2; ++ss) {
            const int s = 2 * h + ss;
            __syncthreads();   // at-tile visible (ss=0); STAGE(s) complete
            f16x8 af[8], bf[4];
#pragma unroll
            for (int i = 0; i < 8; ++i)
                af[i] = *(const f16x8*)(Alds + (wm + i * 16 + lr) * 32 + swz);
#pragma unroll
            for (int j = 0; j < 4; ++j)
                bf[j] = *(const f16x8*)(&qt[wn + j * 16 + lr][ss * 32 + kg * 8]);
            __syncthreads();   // frag reads done; Alds/qt free
            if (s < 15) STAGEF(s + 1);
#pragma unroll
            for (int i = 0; i < 8; ++i)
#pragma unroll
                for (int j = 0; j < 4; ++j)
                    acc[i][j] = __builtin_amdgcn_mfma_f32_16x16x32_f16(af[i], bf[j], acc[i][j], 0, 0, 0);
        }
    }
#undef STAGEF

    // ---- epilogue: y = acc*2^-27 + bias; LN; residual ----
#pragma unroll
    for (int i = 0; i < 8; ++i) {
        const int o = wm + i * 16 + kg * 4;
        const float4 bb = *(const float4*)(b_out + o);
#pragma unroll
        for (int j = 0; j < 4; ++j) {
            acc[i][j][0] = acc[i][j][0] * (1.f / 134217728.f) + bb.x;
            acc[i][j][1] = acc[i][j][1] * (1.f / 134217728.f) + bb.y;
            acc[i][j][2] = acc[i][j][2] * (1.f / 134217728.f) + bb.z;
            acc[i][j][3] = acc[i][j][3] * (1.f / 134217728.f) + bb.w;
        }
    }
    float s1[4], s2[4];
#pragma unroll
    for (int j = 0; j < 4; ++j) {
        s1[j] = 0.f; s2[j] = 0.f;
#pragma unroll
        for (int i = 0; i < 8; ++i)
#pragma unroll
            for (int r = 0; r < 4; ++r) {
                const float v = acc[i][j][r];
                s1[j] += v; s2[j] += v * v;
            }
        s1[j] += __shfl_xor(s1[j], 16); s1[j] += __shfl_xor(s1[j], 32);
        s2[j] += __shfl_xor(s2[j], 16); s2[j] += __shfl_xor(s2[j], 32);
    }
    if (kg == 0) {
#pragma unroll
        for (int j = 0; j < 4; ++j) {
            red1[wv >> 1][wn + j * 16 + lr] = s1[j];
            red2[wv >> 1][wn + j * 16 + lr] = s2[j];
        }
    }
    __syncthreads();
    if (tid < 128) {
        const float S1 = red1[0][tid] + red1[1][tid] + red1[2][tid] + red1[3][tid];
        const float S2 = red2[0][tid] + red2[1][tid] + red2[2][tid] + red2[3][tid];
        const float m = S1 * (1.f / 512.f);
        float var = S2 * (1.f / 512.f) - m * m;
        var = fmaxf(var, 0.f);
        mnS[tid] = m;
        rsS[tid] = rsqrtf(var + LN_EPS);
    }
    __syncthreads();
    float mj[4], rj[4];
#pragma unroll
    for (int j = 0; j < 4; ++j) {
        const int px = wn + j * 16 + lr;
        mj[j] = mnS[px]; rj[j] = rsS[px];
    }
#pragma unroll
    for (int i = 0; i < 8; ++i) {
        const int o = wm + i * 16 + kg * 4;
        const float4 gg = *(const float4*)(g_out + o);
#pragma unroll
        for (int r = 0; r < 4; ++r) {
            const float g = (r == 0) ? gg.x : (r == 1) ? gg.y : (r == 2) ? gg.z : gg.w;
            const float* xr = x + ((size_t)b * CCH + o + r) * HWN + hw0 + wn;
            float* dr = out + ((size_t)b * CCH + o + r) * HWN + hw0 + wn;
#pragma unroll
            for (int j = 0; j < 4; ++j) {
                const int c = j * 16 + lr;
                dr[c] = (acc[i][j][r] - mj[j]) * rj[j] * g + xr[c];
            }
        }
    }
}

// ---------------------------------------------------------------------------
extern "C" void kernel_launch(void* const* d_in, const int* in_sizes, int n_in,
                              void* d_out, int out_size, void* d_ws, size_t ws_size,
                              hipStream_t stream) {
    (void)in_sizes; (void)n_in; (void)out_size;
    const float* x     = (const float*)d_in[0];
    const float* w_qkv = (const float*)d_in[1];
    const float* w_out = (const float*)d_in[2];
    const float* b_out = (const float*)d_in[3];
    const float* g_out = (const float*)d_in[4];
    const float* g_ln  = (const float*)d_in[5];
    float* out = (float*)d_out;
    float* ws  = (float*)d_ws;

    float* s    = ws;                       // 1536
    h16*  ctt   = (h16*)(s + OC3);          // 524288 halfs
    float* ctp  = s + OC3 + 524288;         // 8650752 (128 bh x 16 ci x 4224)
    float* psum = ctp;                      // 524288 (alias: dead before ctx)
    float* psq  = psum + 524288;            // 524288
    h16*  wg_hi = (h16*)(ctp + 8650752);    // 786432 halfs
    h16*  wo_hi = wg_hi + 786432;           // 262144 halfs
    h16*  qkv16 = wo_hi + 262144;           // 100663296 halfs (fp16 q,k,v)
    // alias of d_out: xt dead after qkv_gemm (out_fused is sole d_out writer)
    h16*  xt_hi = (h16*)d_out;

    const size_t need = 60032512ULL * 4ULL;   // ~240.1 MB
    if (ws_size < need) return;

    transpose_prep<<<dim3(64, 8, 17), 256, 0, stream>>>(x, xt_hi, psum, psq,
                                                        w_qkv, g_ln, w_out,
                                                        wg_hi, s, wo_hi);
    qkv_gemm     <<<dim3(12, 256), 512, 0, stream>>>(wg_hi, xt_hi,
                                                     s, psum, psq, qkv16);
    ctx_partial  <<<dim3(16, 128), 64, 0, stream>>>(qkv16, ctp);
    ctx_reduce   <<<128, 256, 0, stream>>>(ctp, ctt);
    out_fused    <<<512, 512, 0, stream>>>(wo_hi, qkv16, ctt,
                                           b_out, g_out, x, out);
}

// Round 23
// 375.659 us; speedup vs baseline: 1.0397x; 1.0397x over previous
//
#include <hip/hip_runtime.h>
#include <math.h>

#define CCH    512
#define HWN    4096
#define NPIX   65536
#define OC3    1536
#define QSCALE 0.125f
#define LN_EPS 1e-5f

typedef _Float16 h16;
typedef h16  f16x8 __attribute__((ext_vector_type(8)));
typedef h16  f16x4 __attribute__((ext_vector_type(4)));
typedef float f32x4 __attribute__((ext_vector_type(4)));

__device__ __forceinline__ float waveReduceSum(float v) {
#pragma unroll
    for (int off = 32; off; off >>= 1) v += __shfl_xor(v, off);
    return v;
}

__device__ __forceinline__ void gl_lds16(const void* g, void* l) {
    __builtin_amdgcn_global_load_lds((const __attribute__((address_space(1))) void*)g,
                                     (__attribute__((address_space(3))) void*)l, 16, 0, 0);
}

// ---------------------------------------------------------------------------
// fused: z<16  -> fp32 x -> transposed fp16 [16][4096][512] + LN partials
//        z==16 -> weight prep (wave = one row)
__global__ __launch_bounds__(256) void transpose_prep(const float* __restrict__ src,
                                                      h16* __restrict__ dhi,
                                                      float* __restrict__ psum,
                                                      float* __restrict__ psq,
                                                      const float* __restrict__ w_qkv,
                                                      const float* __restrict__ g_ln,
                                                      const float* __restrict__ w_out,
                                                      h16* __restrict__ wg_h,
                                                      float* __restrict__ s,
                                                      h16* __restrict__ wo_h) {
    __shared__ float tile[64][65];
    __shared__ float ps1[4][64], ps2[4][64];
    const int t = threadIdx.x;

    if (blockIdx.z == 16) {
        const int o = (blockIdx.x + 64 * blockIdx.y) * 4 + (t >> 6);
        const int lane = t & 63;
        if (o < OC3) {
            float sum = 0.f;
#pragma unroll
            for (int j = 0; j < 8; ++j) {
                const int c = lane + j * 64;
                const float w = w_qkv[(size_t)o * CCH + c] * g_ln[c];
                wg_h[(size_t)o * CCH + c] = (h16)(w * 64.f);
                sum += w;
            }
            sum = waveReduceSum(sum);
            if (lane == 0) s[o] = sum;
        } else {
            const int r = o - OC3;
#pragma unroll
            for (int j = 0; j < 8; ++j) {
                const int c = lane + j * 64;
                wo_h[(size_t)r * CCH + c] = (h16)(w_out[(size_t)r * CCH + c] * 64.f);
            }
        }
        return;
    }

    const int b = blockIdx.z, c0 = blockIdx.y * 64, p0 = blockIdx.x * 64;
    const float* sb = src + ((size_t)b * CCH + c0) * HWN + p0;
    const int rc = t >> 4, cc4 = (t & 15) * 4;
#pragma unroll
    for (int ps = 0; ps < 4; ++ps) {
        const float4 v = *(const float4*)(sb + (size_t)(rc + ps * 16) * HWN + cc4);
        tile[rc + ps * 16][cc4 + 0] = v.x;
        tile[rc + ps * 16][cc4 + 1] = v.y;
        tile[rc + ps * 16][cc4 + 2] = v.z;
        tile[rc + ps * 16][cc4 + 3] = v.w;
    }
    __syncthreads();
    {
        const int q = t >> 6, px = t & 63;
        float s1 = 0.f, s2 = 0.f;
#pragma unroll
        for (int c = q * 16; c < q * 16 + 16; ++c) {
            const float v = tile[c][px];
            s1 += v; s2 += v * v;
        }
        ps1[q][px] = s1; ps2[q][px] = s2;
    }
    const int pr0 = t >> 3, cs = (t & 7) * 8;
#pragma unroll
    for (int ps = 0; ps < 2; ++ps) {
        const int pr = pr0 + ps * 32;
        f16x8 vh;
#pragma unroll
        for (int q = 0; q < 8; ++q) vh[q] = (h16)tile[cs + q][pr];
        const size_t o = ((size_t)b * HWN + p0 + pr) * CCH + c0 + cs;
        *(f16x8*)(dhi + o) = vh;
    }
    __syncthreads();
    if (t < 64) {
        const float s1 = ps1[0][t] + ps1[1][t] + ps1[2][t] + ps1[3][t];
        const float s2 = ps2[0][t] + ps2[1][t] + ps2[2][t] + ps2[3][t];
        const size_t gp = (size_t)b * HWN + p0 + t;
        psum[(size_t)(c0 >> 6) * NPIX + gp] = s1;
        psq [(size_t)(c0 >> 6) * NPIX + gp] = s2;
    }
}

// ---------------------------------------------------------------------------
// QKV GEMM: 128x256 tile, BK=64 two-plane LDS, 512 threads (8 waves of 64x64).
// Single fp16 (A x64 scaled). LN stats finished in-block from psum/psq.
// out fp16 = rstd[p]*(acc/64 - mean[p]*s[o]).
__global__ __launch_bounds__(512) void qkv_gemm(const h16* __restrict__ Ahg,
                                                const h16* __restrict__ Bhg,
                                                const float* __restrict__ sv,
                                                const float* __restrict__ psum,
                                                const float* __restrict__ psq,
                                                h16* __restrict__ qout) {
    __shared__ __align__(16) h16 Ah[8192];
    __shared__ __align__(16) h16 Bh[16384];
    __shared__ float mnS[256], rsS[256];
    const int tid = threadIdx.x;
    const int om = blockIdx.x * 128;
    const int by0 = blockIdx.y;
    const int by  = (by0 & 7) * 32 + (by0 >> 3);
    const int p0  = by * 256;

    const int srow = tid >> 2;
    const int skh  = ((tid & 3) ^ (srow & 3)) * 8;
    const size_t a0 = (size_t)(om + srow) * CCH + skh;
    const size_t b0 = (size_t)(p0 + srow) * CCH + skh;

    const int lane = tid & 63;
    const int wv = tid >> 6;
    const int wm = (wv >> 2) * 64, wn = (wv & 3) * 64;
    const int lr = lane & 15, kg = lane >> 4;
    const int swz = (kg ^ (lr & 3)) * 8;

    f32x4 acc[4][4];
#pragma unroll
    for (int i = 0; i < 4; ++i)
#pragma unroll
        for (int j = 0; j < 4; ++j) acc[i][j] = {0.f, 0.f, 0.f, 0.f};

#define STAGE(KC)                                                          \
    do {                                                                   \
        gl_lds16(Ahg + a0 + (KC),                 Ah + tid * 8);           \
        gl_lds16(Ahg + a0 + (KC) + 32,            Ah + 4096 + tid * 8);    \
        gl_lds16(Bhg + b0 + (KC),                 Bh + tid * 8);           \
        gl_lds16(Bhg + b0 + (KC) + 128 * CCH,     Bh + 4096 + tid * 8);    \
        gl_lds16(Bhg + b0 + (KC) + 32,            Bh + 8192 + tid * 8);    \
        gl_lds16(Bhg + b0 + (KC) + 32 + 128 * CCH, Bh + 12288 + tid * 8);  \
    } while (0)

    STAGE(0);
    if (tid < 256) {
        const int gp = p0 + tid;
        float s1 = 0.f, s2 = 0.f;
#pragma unroll
        for (int cb = 0; cb < 8; ++cb) {
            s1 += psum[(size_t)cb * NPIX + gp];
            s2 += psq [(size_t)cb * NPIX + gp];
        }
        const float m = s1 * (1.f / 512.f);
        float var = s2 * (1.f / 512.f) - m * m;
        var = fmaxf(var, 0.f);
        mnS[tid] = m;
        rsS[tid] = rsqrtf(var + LN_EPS);
    }

#pragma unroll 1
    for (int kc = 0; kc < 512; kc += 64) {
        __syncthreads();
        f16x8 a0f[4], b0f[4], a1f[4], b1f[4];
#pragma unroll
        for (int i = 0; i < 4; ++i) {
            a0f[i] = *(const f16x8*)(Ah + (wm + i * 16 + lr) * 32 + swz);
            b0f[i] = *(const f16x8*)(Bh + (wn + i * 16 + lr) * 32 + swz);
        }
#pragma unroll
        for (int i = 0; i < 4; ++i)
#pragma unroll
            for (int j = 0; j < 4; ++j)
                acc[i][j] = __builtin_amdgcn_mfma_f32_16x16x32_f16(a0f[i], b0f[j], acc[i][j], 0, 0, 0);
#pragma unroll
        for (int i = 0; i < 4; ++i) {
            a1f[i] = *(const f16x8*)(Ah + 4096 + (wm + i * 16 + lr) * 32 + swz);
            b1f[i] = *(const f16x8*)(Bh + 8192 + (wn + i * 16 + lr) * 32 + swz);
        }
        __syncthreads();
        if (kc + 64 < 512) STAGE(kc + 64);
#pragma unroll
        for (int i = 0; i < 4; ++i)
#pragma unroll
            for (int j = 0; j < 4; ++j)
                acc[i][j] = __builtin_amdgcn_mfma_f32_16x16x32_f16(a1f[i], b1f[j], acc[i][j], 0, 0, 0);
    }
#undef STAGE

    const int b = p0 >> 12, hw0 = p0 & 4095;
    float mn[4], rs[4];
#pragma unroll
    for (int j = 0; j < 4; ++j) {
        const int px = wn + j * 16 + lr;
        mn[j] = mnS[px]; rs[j] = rsS[px];
    }
#pragma unroll
    for (int i = 0; i < 4; ++i)
#pragma unroll
        for (int r = 0; r < 4; ++r) {
            const int o = om + wm + i * 16 + kg * 4 + r;
            const float so = sv[o];
            h16* dst = qout + ((size_t)b * OC3 + o) * HWN;
#pragma unroll
            for (int j = 0; j < 4; ++j) {
                const int hw = hw0 + wn + j * 16 + lr;
                dst[hw] = (h16)(rs[j] * (acc[i][j][r] * (1.f / 64.f) - mn[j] * so));
            }
        }
}

// ---------------------------------------------------------------------------
// MFMA context partial over a 256-pixel chunk (1 wave, no LDS, no barriers).
__global__ __launch_bounds__(64) void ctx_partial(const h16* __restrict__ qkv16,
                                                  float* __restrict__ ctp) {
    const int bh = blockIdx.y, ci = blockIdx.x;
    const int b = bh >> 3, h = bh & 7;
    const h16* kb = qkv16 + ((size_t)b * OC3 + CCH  + h * 64) * HWN;
    const h16* vb = qkv16 + ((size_t)b * OC3 + 1024 + h * 64) * HWN;
    const int lane = threadIdx.x;
    const int lr = lane & 15, kg = lane >> 4;
    const int nbase = ci * 256 + kg * 8;

    float m[4] = {-1e30f, -1e30f, -1e30f, -1e30f};
#pragma unroll 1
    for (int c = 0; c < 8; ++c) {
        const int n0 = nbase + c * 32;
#pragma unroll
        for (int i = 0; i < 4; ++i) {
            const f16x8 kv = *(const f16x8*)(kb + (size_t)(i * 16 + lr) * HWN + n0);
#pragma unroll
            for (int u = 0; u < 8; ++u) m[i] = fmaxf(m[i], (float)kv[u]);
        }
    }
#pragma unroll
    for (int i = 0; i < 4; ++i) {
        m[i] = fmaxf(m[i], __shfl_xor(m[i], 16));
        m[i] = fmaxf(m[i], __shfl_xor(m[i], 32));
    }

    float z[4] = {0.f, 0.f, 0.f, 0.f};
    f32x4 acc[4][4];
#pragma unroll
    for (int i = 0; i < 4; ++i)
#pragma unroll
        for (int j = 0; j < 4; ++j) acc[i][j] = {0.f, 0.f, 0.f, 0.f};

#pragma unroll 1
    for (int c = 0; c < 8; ++c) {
        const int n0 = nbase + c * 32;
        f16x8 ke[4], vf[4];
#pragma unroll
        for (int j = 0; j < 4; ++j)
            vf[j] = *(const f16x8*)(vb + (size_t)(j * 16 + lr) * HWN + n0);
#pragma unroll
        for (int i = 0; i < 4; ++i) {
            const f16x8 kv = *(const f16x8*)(kb + (size_t)(i * 16 + lr) * HWN + n0);
            f16x8 t;
#pragma unroll
            for (int u = 0; u < 8; ++u) {
                const float e = __expf((float)kv[u] - m[i]);
                z[i] += e;
                t[u] = (h16)e;
            }
            ke[i] = t;
        }
#pragma unroll
        for (int i = 0; i < 4; ++i)
#pragma unroll
            for (int j = 0; j < 4; ++j)
                acc[i][j] = __builtin_amdgcn_mfma_f32_16x16x32_f16(ke[i], vf[j], acc[i][j], 0, 0, 0);
    }
#pragma unroll
    for (int i = 0; i < 4; ++i) {
        z[i] += __shfl_xor(z[i], 16);
        z[i] += __shfl_xor(z[i], 32);
    }
    float* dst = ctp + ((size_t)bh * 16 + ci) * 4224;
#pragma unroll
    for (int i = 0; i < 4; ++i)
#pragma unroll
        for (int j = 0; j < 4; ++j)
#pragma unroll
            for (int r = 0; r < 4; ++r)
                dst[(i * 16 + kg * 4 + r) * 64 + j * 16 + lr] = acc[i][j][r];
    if (kg == 0)
#pragma unroll
        for (int i = 0; i < 4; ++i) {
            dst[4096 + i * 16 + lr] = z[i];
            dst[4160 + i * 16 + lr] = m[i];
        }
}

// ---------------------------------------------------------------------------
// combine 16 chunk partials with exp(m_loc - M) rescale, normalize, and emit
// TRANSPOSED fp16: ctt[e][d]
__global__ __launch_bounds__(256) void ctx_reduce(const float* __restrict__ ctp,
                                                  h16* __restrict__ ctt) {
    __shared__ float w[16][64];
    __shared__ float rz[64];
    const int bh = blockIdx.x;
    const int tid = threadIdx.x;
    const float* src = ctp + (size_t)bh * 16 * 4224;
    if (tid < 64) {
        float M = -1e30f;
#pragma unroll
        for (int ci = 0; ci < 16; ++ci)
            M = fmaxf(M, src[(size_t)ci * 4224 + 4160 + tid]);
        float Z = 0.f;
#pragma unroll
        for (int ci = 0; ci < 16; ++ci) {
            const float ww = __expf(src[(size_t)ci * 4224 + 4160 + tid] - M);
            w[ci][tid] = ww;
            Z += ww * src[(size_t)ci * 4224 + 4096 + tid];
        }
        rz[tid] = 1.f / Z;
    }
    __syncthreads();
    h16* dstt = ctt + (size_t)bh * 4096;
    for (int e4 = tid * 4; e4 < 4096; e4 += 1024) {
        const int d = e4 >> 6, e0 = e4 & 63;
        float4 sum = make_float4(0.f, 0.f, 0.f, 0.f);
#pragma unroll
        for (int ci = 0; ci < 16; ++ci) {
            const float4 v = *(const float4*)(src + (size_t)ci * 4224 + e4);
            const float ww = w[ci][d];
            sum.x += ww * v.x; sum.y += ww * v.y;
            sum.z += ww * v.z; sum.w += ww * v.w;
        }
        const float r = rz[d];
        dstt[(e0 + 0) * 64 + d] = (h16)(sum.x * r);
        dstt[(e0 + 1) * 64 + d] = (h16)(sum.y * r);
        dstt[(e0 + 2) * 64 + d] = (h16)(sum.z * r);
        dstt[(e0 + 3) * 64 + d] = (h16)(sum.w * r);
    }
}

// ---------------------------------------------------------------------------
// MEGA out kernel: per head h = 0..7:
//   A1: q[64d x 128px] (coalesced) -> qt[px][d] LDS
//   A2: q-softmax over d (4 lanes/px), qtilde fp16 in place (x 512*QSCALE)
//   A3: PV MFMA (A = ctt reg frags, B = qtilde) -> at-tile fp16 back into qt
//   A4: 2 GEMM K-steps: acc += wo(s) . at-tile
// epilogue: y = acc*2^-27 + bias; channel-LN; out = LN(y)*g_out + x.
__global__ __launch_bounds__(512) void out_fused(const h16* __restrict__ wo_hi,
                                                 const h16* __restrict__ qkv16,
                                                 const h16* __restrict__ ctt,
                                                 const float* __restrict__ b_out,
                                                 const float* __restrict__ g_out,
                                                 const float* __restrict__ x,
                                                 float* __restrict__ out) {
    __shared__ __align__(16) h16 Alds[512 * 32];   // 32 KB, one K-step
    __shared__ __align__(16) h16 qt[128][72];      // 18.4 KB; q / qtilde / at-tile
    __shared__ float red1[4][128], red2[4][128];
    __shared__ float mnS[128], rsS[128];

    const int tid = threadIdx.x;
    const int p0 = blockIdx.x * 128;
    const int b = p0 >> 12, hw0 = p0 & 4095;

    const int trow = tid >> 2;
    const int skh  = ((tid & 3) ^ (trow & 3)) * 8;
    const size_t aoff = (size_t)trow * CCH + skh;
    const int wofs = (tid >> 6) * 512;

    const int wv = tid >> 6;
    const int lane = tid & 63;
    const int lr = lane & 15, kg = lane >> 4;
    const int wm = (wv >> 1) * 128, wn = (wv & 1) * 64;   // GEMM map
    const int swz = (kg ^ (lr & 3)) * 8;
    const int pv_e0 = (wv & 3) * 16, pv_ph = (wv >> 2) * 64;   // PV map
    const int sm_px = tid >> 2, sm_d0 = (tid & 3) * 16;        // softmax map
    const int ql_d = tid >> 3, ql_px = (tid & 7) * 16;         // q-load map

    f32x4 acc[8][4];
#pragma unroll
    for (int i = 0; i < 8; ++i)
#pragma unroll
        for (int j = 0; j < 4; ++j) acc[i][j] = {0.f, 0.f, 0.f, 0.f};

#define STAGEF(S)                                                           \
    do {                                                                    \
        const int kc_ = (S) * 32;                                           \
        gl_lds16(wo_hi + aoff + kc_,               Alds + wofs);            \
        gl_lds16(wo_hi + aoff + kc_ + 128 * CCH,   Alds + 4096 + wofs);     \
        gl_lds16(wo_hi + aoff + kc_ + 256 * CCH,   Alds + 8192 + wofs);     \
        gl_lds16(wo_hi + aoff + kc_ + 384 * CCH,   Alds + 12288 + wofs);    \
    } while (0)

    STAGEF(0);

#pragma unroll 1
    for (int h = 0; h < 8; ++h) {
        const h16* qb = qkv16 + ((size_t)b * OC3 + h * 64) * HWN + hw0;
        // ---- A1: q load -> qt[px][d] ----
        {
            const f16x8 q0 = *(const f16x8*)(qb + (size_t)ql_d * HWN + ql_px);
            const f16x8 q1 = *(const f16x8*)(qb + (size_t)ql_d * HWN + ql_px + 8);
#pragma unroll
            for (int u = 0; u < 8; ++u) {
                qt[ql_px + u][ql_d]     = q0[u];
                qt[ql_px + 8 + u][ql_d] = q1[u];
            }
        }
        __syncthreads();
        // ---- A2: softmax over d ----
        {
            float qv[16];
            float mx = -1e30f;
#pragma unroll
            for (int dd = 0; dd < 16; ++dd) {
                qv[dd] = (float)qt[sm_px][sm_d0 + dd];
                mx = fmaxf(mx, qv[dd]);
            }
            mx = fmaxf(mx, __shfl_xor(mx, 1));
            mx = fmaxf(mx, __shfl_xor(mx, 2));
            float sm = 0.f;
#pragma unroll
            for (int dd = 0; dd < 16; ++dd) {
                qv[dd] = __expf(qv[dd] - mx);
                sm += qv[dd];
            }
            sm += __shfl_xor(sm, 1);
            sm += __shfl_xor(sm, 2);
            const float sc = 512.f * QSCALE / sm;
#pragma unroll
            for (int dd = 0; dd < 16; ++dd)
                qt[sm_px][sm_d0 + dd] = (h16)(qv[dd] * sc);
        }
        __syncthreads();
        // ---- A3: PV MFMA -> at-tile ----
        {
            const h16* cb = ctt + ((size_t)(b * 8 + h)) * 4096 + (pv_e0 + lr) * 64 + kg * 8;
            const f16x8 af0 = *(const f16x8*)(cb);
            const f16x8 af1 = *(const f16x8*)(cb + 32);
            f32x4 acc4[4];
#pragma unroll
            for (int j = 0; j < 4; ++j) acc4[j] = {0.f, 0.f, 0.f, 0.f};
#pragma unroll
            for (int j = 0; j < 4; ++j) {
                const int px = pv_ph + j * 16 + lr;
                const f16x8 bf0 = *(const f16x8*)(&qt[px][kg * 8]);
                const f16x8 bf1 = *(const f16x8*)(&qt[px][32 + kg * 8]);
                acc4[j] = __builtin_amdgcn_mfma_f32_16x16x32_f16(af0, bf0, acc4[j], 0, 0, 0);
                acc4[j] = __builtin_amdgcn_mfma_f32_16x16x32_f16(af1, bf1, acc4[j], 0, 0, 0);
            }
            __syncthreads();   // qtilde reads done; qt becomes at-tile
#pragma unroll
            for (int j = 0; j < 4; ++j) {
                f16x4 o4;
                o4[0] = (h16)acc4[j][0]; o4[1] = (h16)acc4[j][1];
                o4[2] = (h16)acc4[j][2]; o4[3] = (h16)acc4[j][3];
                *(f16x4*)(&qt[pv_ph + j * 16 + lr][pv_e0 + kg * 4]) = o4;
            }
        }
        // ---- A4: 2 GEMM K-steps consuming at-tile ----
#pragma unroll 1
        for (int ss = 0; ss < 2; ++ss) {
            const int s = 2 * h + ss;
            __syncthreads();   // at-tile visible (ss=0); STAGE(s) complete
            f16x8 af[8], bf[4];
#pragma unroll
            for (int i = 0; i < 8; ++i)
                af[i] = *(const f16x8*)(Alds + (wm + i * 16 + lr) * 32 + swz);
#pragma unroll
            for (int j = 0; j < 4; ++j)
                bf[j] = *(const f16x8*)(&qt[wn + j * 16 + lr][ss * 32 + kg * 8]);
            __syncthreads();   // frag reads done; Alds/qt free
            if (s < 15) STAGEF(s + 1);
#pragma unroll
            for (int i = 0; i < 8; ++i)
#pragma unroll
                for (int j = 0; j < 4; ++j)
                    acc[i][j] = __builtin_amdgcn_mfma_f32_16x16x32_f16(af[i], bf[j], acc[i][j], 0, 0, 0);
        }
    }
#undef STAGEF

    // ---- epilogue: y = acc*2^-27 + bias; LN; residual ----
#pragma unroll
    for (int i = 0; i < 8; ++i) {
        const int o = wm + i * 16 + kg * 4;
        const float4 bb = *(const float4*)(b_out + o);
#pragma unroll
        for (int j = 0; j < 4; ++j) {
            acc[i][j][0] = acc[i][j][0] * (1.f / 134217728.f) + bb.x;
            acc[i][j][1] = acc[i][j][1] * (1.f / 134217728.f) + bb.y;
            acc[i][j][2] = acc[i][j][2] * (1.f / 134217728.f) + bb.z;
            acc[i][j][3] = acc[i][j][3] * (1.f / 134217728.f) + bb.w;
        }
    }
    float s1[4], s2[4];
#pragma unroll
    for (int j = 0; j < 4; ++j) {
        s1[j] = 0.f; s2[j] = 0.f;
#pragma unroll
        for (int i = 0; i < 8; ++i)
#pragma unroll
            for (int r = 0; r < 4; ++r) {
                const float v = acc[i][j][r];
                s1[j] += v; s2[j] += v * v;
            }
        s1[j] += __shfl_xor(s1[j], 16); s1[j] += __shfl_xor(s1[j], 32);
        s2[j] += __shfl_xor(s2[j], 16); s2[j] += __shfl_xor(s2[j], 32);
    }
    if (kg == 0) {
#pragma unroll
        for (int j = 0; j < 4; ++j) {
            red1[wv >> 1][wn + j * 16 + lr] = s1[j];
            red2[wv >> 1][wn + j * 16 + lr] = s2[j];
        }
    }
    __syncthreads();
    if (tid < 128) {
        const float S1 = red1[0][tid] + red1[1][tid] + red1[2][tid] + red1[3][tid];
        const float S2 = red2[0][tid] + red2[1][tid] + red2[2][tid] + red2[3][tid];
        const float m = S1 * (1.f / 512.f);
        float var = S2 * (1.f / 512.f) - m * m;
        var = fmaxf(var, 0.f);
        mnS[tid] = m;
        rsS[tid] = rsqrtf(var + LN_EPS);
    }
    __syncthreads();
    float mj[4], rj[4];
#pragma unroll
    for (int j = 0; j < 4; ++j) {
        const int px = wn + j * 16 + lr;
        mj[j] = mnS[px]; rj[j] = rsS[px];
    }
#pragma unroll
    for (int i = 0; i < 8; ++i) {
        const int o = wm + i * 16 + kg * 4;
        const float4 gg = *(const float4*)(g_out + o);
#pragma unroll
        for (int r = 0; r < 4; ++r) {
            const float g = (r == 0) ? gg.x : (r == 1) ? gg.y : (r == 2) ? gg.z : gg.w;
            const float* xr = x + ((size_t)b * CCH + o + r) * HWN + hw0 + wn;
            float* dr = out + ((size_t)b * CCH + o + r) * HWN + hw0 + wn;
#pragma unroll
            for (int j = 0; j < 4; ++j) {
                const int c = j * 16 + lr;
                dr[c] = (acc[i][j][r] - mj[j]) * rj[j] * g + xr[c];
            }
        }
    }
}

// ---------------------------------------------------------------------------
extern "C" void kernel_launch(void* const* d_in, const int* in_sizes, int n_in,
                              void* d_out, int out_size, void* d_ws, size_t ws_size,
                              hipStream_t stream) {
    (void)in_sizes; (void)n_in; (void)out_size;
    const float* x     = (const float*)d_in[0];
    const float* w_qkv = (const float*)d_in[1];
    const float* w_out = (const float*)d_in[2];
    const float* b_out = (const float*)d_in[3];
    const float* g_out = (const float*)d_in[4];
    const float* g_ln  = (const float*)d_in[5];
    float* out = (float*)d_out;
    float* ws  = (float*)d_ws;

    float* s    = ws;                       // 1536
    h16*  ctt   = (h16*)(s + OC3);          // 524288 halfs
    float* ctp  = s + OC3 + 524288;         // 8650752 (128 bh x 16 ci x 4224)
    float* psum = ctp;                      // 524288 (alias: dead before ctx)
    float* psq  = psum + 524288;            // 524288
    h16*  wg_hi = (h16*)(ctp + 8650752);    // 786432 halfs
    h16*  wo_hi = wg_hi + 786432;           // 262144 halfs
    h16*  qkv16 = wo_hi + 262144;           // 100663296 halfs (fp16 q,k,v)
    // alias of d_out: xt dead after qkv_gemm (out_fused is sole d_out writer)
    h16*  xt_hi = (h16*)d_out;

    const size_t need = 60032512ULL * 4ULL;   // ~240.1 MB
    if (ws_size < need) return;

    transpose_prep<<<dim3(64, 8, 17), 256, 0, stream>>>(x, xt_hi, psum, psq,
                                                        w_qkv, g_ln, w_out,
                                                        wg_hi, s, wo_hi);
    qkv_gemm     <<<dim3(12, 256), 512, 0, stream>>>(wg_hi, xt_hi,
                                                     s, psum, psq, qkv16);
    ctx_partial  <<<dim3(16, 128), 64, 0, stream>>>(qkv16, ctp);
    ctx_reduce   <<<128, 256, 0, stream>>>(ctp, ctt);
    out_fused    <<<512, 512, 0, stream>>>(wo_hi, qkv16, ctt,
                                           b_out, g_out, x, out);
}